// Round 8
// baseline (656.507 us; speedup 1.0000x reference)
//
#include <hip/hip_runtime.h>
#include <hip/hip_bf16.h>

// Mlp_moe: patch MLP + 6-class 2-route MoE on cls tokens.
// Round 8: big GEMMs go LDS-free ("direct-global" fragments). The MFMA frag pattern read
// straight from row-major global is fully coalesced (16 rows x 64B dense per instr);
// 128^2 tile A+B fits L1. Removes the ~90%-busy LDS port AND all barriers.

typedef __bf16 bf16x8 __attribute__((ext_vector_type(8)));
typedef float f32x4 __attribute__((ext_vector_type(4)));
typedef unsigned short u16;

#define DEVINL __device__ __forceinline__

DEVINL u16 f2bf(float f) {
  unsigned int u = __builtin_bit_cast(unsigned int, f);
  u += 0x7FFFu + ((u >> 16) & 1u);
  return (u16)(u >> 16);
}

// Winitzki erf: abs err ~2e-4 (vs bf16 rounding 0.008), branch-free.
DEVINL float gelu_fast(float v) {
  const float x2 = 0.5f * v * v;
  const float t = x2 * (1.27323954f + 0.147f * x2) / (1.0f + 0.147f * x2);
  const float r = sqrtf(fmaxf(1.0f - __expf(-t), 0.0f));
  const float e = copysignf(r, v);
  return 0.5f * v * (1.0f + e);
}

DEVINL void async_load16(const void* g, void* l) {
  __builtin_amdgcn_global_load_lds(
      (const __attribute__((address_space(1))) unsigned int*)g,
      (__attribute__((address_space(3))) unsigned int*)l, 16, 0, 0);
}

#define MFMA16 __builtin_amdgcn_mfma_f32_16x16x32_bf16

// ---------------- conversions ----------------
__global__ void cvt_x2(const float* __restrict__ x, u16* __restrict__ xc, u16* __restrict__ xp) {
  const int i = blockIdx.x, b = blockIdx.y;
  const int d = threadIdx.x * 4;
  const float4 v = *(const float4*)(x + ((size_t)(b * 203 + i)) * 768 + d);
  ushort4 u;
  u.x = f2bf(v.x); u.y = f2bf(v.y); u.z = f2bf(v.z); u.w = f2bf(v.w);
  if (i < 6) *(ushort4*)(xc + (size_t)(b * 6 + i) * 768 + d) = u;
  else       *(ushort4*)(xp + (size_t)(b * 197 + (i - 6)) * 768 + d) = u;
}

__global__ void cvt_w(const float* __restrict__ s1, u16* __restrict__ d1,
                      const float* __restrict__ s2, u16* __restrict__ d2,
                      const float* __restrict__ s3, u16* __restrict__ d3,
                      const float* __restrict__ s4, u16* __restrict__ d4) {
  int b = blockIdx.x;
  const float* s; u16* d;
  if (b < 2304) { s = s1; d = d1; }
  else if (b < 4608) { s = s2; d = d2; b -= 2304; }
  else if (b < 16128) { s = s3; d = d3; b -= 4608; }
  else { s = s4; d = d4; b -= 16128; }
  const int i = (b * 256 + threadIdx.x) * 4;
  const float4 v = *(const float4*)(s + i);
  ushort4 u;
  u.x = f2bf(v.x); u.y = f2bf(v.y); u.z = f2bf(v.z); u.w = f2bf(v.w);
  *(ushort4*)(d + i) = u;
}

// ---------------- gate / routing decision (fp64 accum) ----------------
__global__ void gate_kernel(const float* __restrict__ x,
                            const float* __restrict__ gate_pair,
                            const float* __restrict__ balance_bias,
                            int* __restrict__ rstar, float* __restrict__ wstar) {
  const int lane = threadIdx.x & 63, wid = threadIdx.x >> 6;
  const int idx = blockIdx.x * 4 + wid;
  const int b = idx / 6, n = idx % 6;
  const float* xv = x + (size_t)(b * 203 + n) * 768;
  const float* w0 = gate_pair + (size_t)(n * 2 + 0) * 768;
  const float* w1 = gate_pair + (size_t)(n * 2 + 1) * 768;
  double xx = 0, a00 = 0, a11 = 0, d0 = 0, d1 = 0;
  for (int d = lane; d < 768; d += 64) {
    double xd = xv[d], g0 = w0[d], g1 = w1[d];
    xx += xd * xd; a00 += g0 * g0; a11 += g1 * g1; d0 += xd * g0; d1 += xd * g1;
  }
#pragma unroll
  for (int off = 32; off; off >>= 1) {
    xx  += __shfl_xor(xx, off);
    a00 += __shfl_xor(a00, off);
    a11 += __shfl_xor(a11, off);
    d0  += __shfl_xor(d0, off);
    d1  += __shfl_xor(d1, off);
  }
  if (lane == 0) {
    double nx = fmax(sqrt(xx), 1e-12), n0 = fmax(sqrt(a00), 1e-12), n1 = fmax(sqrt(a11), 1e-12);
    double l0 = d0 / (nx * n0) + (double)balance_bias[n * 2 + 0];
    double l1 = d1 / (nx * n1) + (double)balance_bias[n * 2 + 1];
    const int r = (l1 > l0) ? 1 : 0;
    double m = fmax(l0, l1);
    double e0 = exp(l0 - m), e1 = exp(l1 - m);
    rstar[idx] = r;
    wstar[idx] = (float)(((r == 1) ? e1 : e0) / (e0 + e1));
  }
}

// ---------------- 128x128 direct-global GEMM (no LDS, no barriers) ----------------
// C = A(MxK) * B(NxK)^T + bias. 4 waves (2Mx2N), wave tile 64x64.
// Frag load: af[im] <- A[tm+wr*64+im*16+(lane&15)][t*64 + (kk*4+(lane>>4))*8 ..+8]
// Per instr: lanes = 16 rows x 4 contiguous 16B chunks = dense 64B lines. L1-friendly.
template <int EPI>
__global__ __launch_bounds__(256, 2) void gemm_dg(
    const u16* __restrict__ A, const u16* __restrict__ B,
    const float* __restrict__ bias, void* __restrict__ Cout,
    int M, int K, int ldc) {
  const int tid = threadIdx.x;
  const int lane = tid & 63, wid = tid >> 6;
  const int wr = wid >> 1, wc = wid & 1;
  const int tm = blockIdx.y * 128, tn = blockIdx.x * 128;
  const int ksteps = K >> 6;
  const int l15 = lane & 15, hi = lane >> 4;

  // per-lane base pointers (loop-invariant except += 64/tile)
  const u16* pa[4];
  const u16* pb[4];
#pragma unroll
  for (int im = 0; im < 4; ++im) {
    int row = tm + wr * 64 + im * 16 + l15;
    row = row < M ? row : (M - 1);  // clamp tail rows (never stored)
    pa[im] = A + (size_t)row * K + hi * 8;
  }
#pragma unroll
  for (int in_ = 0; in_ < 4; ++in_) {
    const int col = tn + wc * 64 + in_ * 16 + l15;
    pb[in_] = B + (size_t)col * K + hi * 8;
  }

  f32x4 acc[4][4] = {};

  for (int t = 0; t < ksteps; ++t) {
    bf16x8 a0[4], a1[4], b0[4], b1[4];
#pragma unroll
    for (int im = 0; im < 4; ++im) {
      a0[im] = *(const bf16x8*)(pa[im]);
      a1[im] = *(const bf16x8*)(pa[im] + 32);  // kk=1: +32 elems (+64B)
    }
#pragma unroll
    for (int in_ = 0; in_ < 4; ++in_) {
      b0[in_] = *(const bf16x8*)(pb[in_]);
      b1[in_] = *(const bf16x8*)(pb[in_] + 32);
    }
#pragma unroll
    for (int im = 0; im < 4; ++im) pa[im] += 64;
#pragma unroll
    for (int in_ = 0; in_ < 4; ++in_) pb[in_] += 64;
#pragma unroll
    for (int im = 0; im < 4; ++im)
#pragma unroll
      for (int in_ = 0; in_ < 4; ++in_)
        acc[im][in_] = MFMA16(a0[im], b0[in_], acc[im][in_], 0, 0, 0);
#pragma unroll
    for (int im = 0; im < 4; ++im)
#pragma unroll
      for (int in_ = 0; in_ < 4; ++in_)
        acc[im][in_] = MFMA16(a1[im], b1[in_], acc[im][in_], 0, 0, 0);
  }

  const int cn = lane & 15, cr4 = (lane >> 4) * 4;
#pragma unroll
  for (int im = 0; im < 4; ++im) {
#pragma unroll
    for (int in_ = 0; in_ < 4; ++in_) {
      const int col = tn + wc * 64 + in_ * 16 + cn;
      const float bv = bias[col];
#pragma unroll
      for (int j = 0; j < 4; ++j) {
        const int row = tm + wr * 64 + im * 16 + cr4 + j;
        if (row < M) {
          const float v = acc[im][in_][j] + bv;
          if (EPI == 0) {
            ((u16*)Cout)[(size_t)row * ldc + col] = f2bf(gelu_fast(v));
          } else {
            const int b = row / 197, pp = row % 197;
            ((float*)Cout)[((size_t)(b * 203 + 6 + pp)) * 768 + col] = v;
          }
        }
      }
    }
  }
}

// ---------------- candidate GEMM: per (n,r,row-half) 32x128 tile (round-7 proven) ----------------
__global__ __launch_bounds__(256, 4) void cand_gemm(
    const u16* __restrict__ hid, const u16* __restrict__ wao,
    const float* __restrict__ bout, const int* __restrict__ rstar,
    const float* __restrict__ wstar, float* __restrict__ out) {
  __shared__ u16 As[2][32 * 64];
  __shared__ u16 Bs[2][128 * 64];
  const int g = blockIdx.y, n = g >> 1, r = g & 1;
  const int src_a = (r == 0) ? (n >> 1) : (3 + (n & 1));
  const int dst_a = (r == 1) ? (n >> 1) : (3 + (n & 1));
  const int tn = blockIdx.x * 128;
  const int b0 = blockIdx.z * 32;
  const int tid = threadIdx.x, lane = tid & 63, wid = tid >> 6;
  const u16* Bbase = wao + (size_t)dst_a * 768 * 3072;
  const u16* Abase = hid + (size_t)src_a * 3072 + (size_t)n * 15360;

  f32x4 acc[2][2] = {};

  auto stage = [&](int buf, int t) {
    const int k0 = t << 6;
    {
      const int row = tid >> 3;  // 0..31
      const int slA = (tid & 7) ^ (row & 7);
      async_load16(Abase + (size_t)(b0 + row) * 6 * 15360 + k0 + slA * 8,
                   (char*)As[buf] + row * 128 + (tid & 7) * 16);
    }
#pragma unroll
    for (int j = 0; j < 4; ++j) {
      const int row = j * 32 + (tid >> 3);  // 0..127
      const int slB = (tid & 7) ^ (row & 7);
      async_load16(Bbase + (size_t)(tn + row) * 3072 + k0 + slB * 8,
                   (char*)Bs[buf] + row * 128 + (tid & 7) * 16);
    }
  };
  auto compute = [&](int buf) {
    const u16* as = As[buf];
    const u16* bs = Bs[buf];
#pragma unroll
    for (int kk = 0; kk < 2; ++kk) {
      bf16x8 af[2], bfv[2];
#pragma unroll
      for (int im = 0; im < 2; ++im) {
        const int R = im * 16 + (lane & 15);
        const int s = (kk * 4 + (lane >> 4)) ^ (R & 7);
        af[im] = *(const bf16x8*)(as + R * 64 + s * 8);
      }
#pragma unroll
      for (int q = 0; q < 2; ++q) {
        const int R = wid * 32 + q * 16 + (lane & 15);
        const int s = (kk * 4 + (lane >> 4)) ^ (R & 7);
        bfv[q] = *(const bf16x8*)(bs + R * 64 + s * 8);
      }
#pragma unroll
      for (int im = 0; im < 2; ++im)
#pragma unroll
        for (int q = 0; q < 2; ++q)
          acc[im][q] = MFMA16(af[im], bfv[q], acc[im][q], 0, 0, 0);
    }
  };

  stage(0, 0);
  __syncthreads();
  for (int t = 0; t < 48; ++t) {
    if (t + 1 < 48) stage((t + 1) & 1, t + 1);
    compute(t & 1);
    __syncthreads();
  }

  const int cn = lane & 15, cr4 = (lane >> 4) * 4;
#pragma unroll
  for (int im = 0; im < 2; ++im)
#pragma unroll
    for (int q = 0; q < 2; ++q) {
      const int col = tn + wid * 32 + q * 16 + cn;
      const float bv = bout[dst_a * 768 + col];
#pragma unroll
      for (int j = 0; j < 4; ++j) {
        const int b = b0 + im * 16 + cr4 + j;
        const int idx = b * 6 + n;
        if (rstar[idx] == r)
          out[((size_t)(b * 203 + n)) * 768 + col] = (acc[im][q][j] + bv) * wstar[idx];
      }
    }
}

// ---------------- launch ----------------
extern "C" void kernel_launch(void* const* d_in, const int* in_sizes, int n_in,
                              void* d_out, int out_size, void* d_ws, size_t ws_size,
                              hipStream_t stream) {
  const float* x     = (const float*)d_in[0];
  const float* fc1w  = (const float*)d_in[1];
  const float* fc1b  = (const float*)d_in[2];
  const float* fc2w  = (const float*)d_in[3];
  const float* fc2b  = (const float*)d_in[4];
  const float* gpair = (const float*)d_in[5];
  const float* aiw   = (const float*)d_in[6];
  const float* aib   = (const float*)d_in[7];
  const float* aow   = (const float*)d_in[8];
  const float* aob   = (const float*)d_in[9];
  const float* bbias = (const float*)d_in[10];
  float* out = (float*)d_out;

  char* ws = (char*)d_ws;
  u16* xp   = (u16*)(ws + 0);          // 12608x768 bf16
  u16* xc   = (u16*)(ws + 19365888);   // 384x768
  u16* w1   = (u16*)(ws + 19955712);   // 3072x768
  u16* w2   = (u16*)(ws + 24674304);   // 768x3072
  u16* wai  = (u16*)(ws + 29392896);   // 5x3072x768
  u16* wao  = (u16*)(ws + 52985856);   // 5x768x3072
  u16* hb   = (u16*)(ws + 76578816);   // 12608x3072
  u16* hid  = (u16*)(ws + 154042368);  // 384x15360
  int*   rstar = (int*)(ws + 165838848);
  float* wstar = (float*)(ws + 165840384);
  if (ws_size < 165841920) return;

  cvt_x2<<<dim3(203, 64), 192, 0, stream>>>(x, xc, xp);
  cvt_w<<<27648, 256, 0, stream>>>(fc1w, w1, fc2w, w2, aiw, wai, aow, wao);
  gate_kernel<<<96, 256, 0, stream>>>(x, gpair, bbias, rstar, wstar);
  // patch fc1 + gelu -> hb (bf16), direct-global
  gemm_dg<0><<<dim3(24, 99), 256, 0, stream>>>(xp, w1, fc1b, hb, 12608, 768, 3072);
  // hid_all = gelu(cls @ atom_in_w^T + b), direct-global
  gemm_dg<0><<<dim3(120, 3), 256, 0, stream>>>(xc, wai, aib, hid, 384, 768, 15360);
  // patch fc2 -> d_out (scatter), direct-global
  gemm_dg<1><<<dim3(6, 99), 256, 0, stream>>>(hb, w2, fc2b, out, 12608, 3072, 768);
  // route candidates, chosen one written * prob
  cand_gemm<<<dim3(6, 12, 2), 256, 0, stream>>>(hid, wao, aob, rstar, wstar, out);
}

// Round 10
// 363.051 us; speedup vs baseline: 1.8083x; 1.8083x over previous
//
#include <hip/hip_runtime.h>
#include <hip/hip_bf16.h>

// Mlp_moe: patch MLP + 6-class 2-route MoE on cls tokens.
// Round 10: round-9 8-phase counted-vmcnt schedule with the builtin-name typo fixed
// (__builtin_amdgcn_global_load_lds). Schedule: 128^2, 4 waves, 64KB LDS, vmcnt(6)@ph4/ph8.

typedef __bf16 bf16x8 __attribute__((ext_vector_type(8)));
typedef float f32x4 __attribute__((ext_vector_type(4)));
typedef unsigned short u16;

#define DEVINL __device__ __forceinline__

DEVINL u16 f2bf(float f) {
  unsigned int u = __builtin_bit_cast(unsigned int, f);
  u += 0x7FFFu + ((u >> 16) & 1u);
  return (u16)(u >> 16);
}

// Winitzki erf: abs err ~2e-4 (vs bf16 rounding 0.008), branch-free.
DEVINL float gelu_fast(float v) {
  const float x2 = 0.5f * v * v;
  const float t = x2 * (1.27323954f + 0.147f * x2) / (1.0f + 0.147f * x2);
  const float r = sqrtf(fmaxf(1.0f - __expf(-t), 0.0f));
  const float e = copysignf(r, v);
  return 0.5f * v * (1.0f + e);
}

DEVINL void async_load16(const void* g, void* l) {
  __builtin_amdgcn_global_load_lds(
      (const __attribute__((address_space(1))) unsigned int*)g,
      (__attribute__((address_space(3))) unsigned int*)l, 16, 0, 0);
}

#define MFMA16 __builtin_amdgcn_mfma_f32_16x16x32_bf16
#define FENCE asm volatile("" ::: "memory")
DEVINL void bar() { FENCE; __builtin_amdgcn_s_barrier(); FENCE; }
DEVINL void vm6() { asm volatile("s_waitcnt vmcnt(6)" ::: "memory"); }

// ---------------- conversions ----------------
__global__ void cvt_x2(const float* __restrict__ x, u16* __restrict__ xc, u16* __restrict__ xp) {
  const int i = blockIdx.x, b = blockIdx.y;
  const int d = threadIdx.x * 4;
  const float4 v = *(const float4*)(x + ((size_t)(b * 203 + i)) * 768 + d);
  ushort4 u;
  u.x = f2bf(v.x); u.y = f2bf(v.y); u.z = f2bf(v.z); u.w = f2bf(v.w);
  if (i < 6) *(ushort4*)(xc + (size_t)(b * 6 + i) * 768 + d) = u;
  else       *(ushort4*)(xp + (size_t)(b * 197 + (i - 6)) * 768 + d) = u;
}

__global__ void cvt_w(const float* __restrict__ s1, u16* __restrict__ d1,
                      const float* __restrict__ s2, u16* __restrict__ d2,
                      const float* __restrict__ s3, u16* __restrict__ d3,
                      const float* __restrict__ s4, u16* __restrict__ d4) {
  int b = blockIdx.x;
  const float* s; u16* d;
  if (b < 2304) { s = s1; d = d1; }
  else if (b < 4608) { s = s2; d = d2; b -= 2304; }
  else if (b < 16128) { s = s3; d = d3; b -= 4608; }
  else { s = s4; d = d4; b -= 16128; }
  const int i = (b * 256 + threadIdx.x) * 4;
  const float4 v = *(const float4*)(s + i);
  ushort4 u;
  u.x = f2bf(v.x); u.y = f2bf(v.y); u.z = f2bf(v.z); u.w = f2bf(v.w);
  *(ushort4*)(d + i) = u;
}

// ---------------- gate / routing decision (fp64 accum) ----------------
__global__ void gate_kernel(const float* __restrict__ x,
                            const float* __restrict__ gate_pair,
                            const float* __restrict__ balance_bias,
                            int* __restrict__ rstar, float* __restrict__ wstar) {
  const int lane = threadIdx.x & 63, wid = threadIdx.x >> 6;
  const int idx = blockIdx.x * 4 + wid;
  const int b = idx / 6, n = idx % 6;
  const float* xv = x + (size_t)(b * 203 + n) * 768;
  const float* w0 = gate_pair + (size_t)(n * 2 + 0) * 768;
  const float* w1 = gate_pair + (size_t)(n * 2 + 1) * 768;
  double xx = 0, a00 = 0, a11 = 0, d0 = 0, d1 = 0;
  for (int d = lane; d < 768; d += 64) {
    double xd = xv[d], g0 = w0[d], g1 = w1[d];
    xx += xd * xd; a00 += g0 * g0; a11 += g1 * g1; d0 += xd * g0; d1 += xd * g1;
  }
#pragma unroll
  for (int off = 32; off; off >>= 1) {
    xx  += __shfl_xor(xx, off);
    a00 += __shfl_xor(a00, off);
    a11 += __shfl_xor(a11, off);
    d0  += __shfl_xor(d0, off);
    d1  += __shfl_xor(d1, off);
  }
  if (lane == 0) {
    double nx = fmax(sqrt(xx), 1e-12), n0 = fmax(sqrt(a00), 1e-12), n1 = fmax(sqrt(a11), 1e-12);
    double l0 = d0 / (nx * n0) + (double)balance_bias[n * 2 + 0];
    double l1 = d1 / (nx * n1) + (double)balance_bias[n * 2 + 1];
    const int r = (l1 > l0) ? 1 : 0;
    double m = fmax(l0, l1);
    double e0 = exp(l0 - m), e1 = exp(l1 - m);
    rstar[idx] = r;
    wstar[idx] = (float)(((r == 1) ? e1 : e0) / (e0 + e1));
  }
}

// ---------------- 128x128 8-phase pipelined GEMM ----------------
// C = A(MxK)*B(NxK)^T + bias. 4 waves (2Mx2N), wave tile 64x64, BK=64, K-tiles even >=2.
// LDS 64KB: Abuf0@0, Abuf1@16K, Bbuf0@32K, Bbuf1@48K; halves = 64 rows (8KB, 2 loads/thr).
// Per tile 4 phases (m0,n0)(m0,n1)(m1,n1)(m1,n0); B fully reg-loaded at n0-phase.
// Stage 1 half/phase into the slot freed one phase earlier; vmcnt(6) at ph4/ph8 only.
template <int EPI>
__global__ __launch_bounds__(256, 2) void gemm8p(
    const u16* __restrict__ A, const u16* __restrict__ B,
    const float* __restrict__ bias, void* __restrict__ Cout,
    int M, int K, int ldc) {
  __shared__ char lds[65536];
  const int tid = threadIdx.x;
  const int lane = tid & 63, wid = tid >> 6;
  const int wr = wid >> 1, wc = wid & 1;
  const int tm = blockIdx.y * 128, tn = blockIdx.x * 128;
  const int kt = K >> 6;

  const int srow = tid >> 3, sslot = tid & 7;
  const int l15 = lane & 15, q4 = lane >> 4;

  f32x4 acc[4][4] = {};
  bf16x8 am[2][2], bv[4][2];

  // stage: buffer parity from UNclamped tau; source k-tile clamped (idempotent tail).
  auto stageA = [&](int tau, int h) {
    const int tc = tau < kt ? tau : kt - 1;
    const int sl = sslot ^ (srow & 7);
    char* dst = lds + (tau & 1) * 16384 + (h * 64 + srow) * 128 + sslot * 16;
    const u16* src = A + (size_t)tc * 64 + sl * 8;
    int g0 = tm + h * 64 + srow;      g0 = g0 < M ? g0 : M - 1;
    int g1 = tm + h * 64 + 32 + srow; g1 = g1 < M ? g1 : M - 1;
    async_load16(src + (size_t)g0 * K, dst);
    async_load16(src + (size_t)g1 * K, dst + 4096);
  };
  auto stageB = [&](int tau, int h) {
    const int tc = tau < kt ? tau : kt - 1;
    const int sl = sslot ^ (srow & 7);
    char* dst = lds + 32768 + (tau & 1) * 16384 + (h * 64 + srow) * 128 + sslot * 16;
    const u16* src = B + (size_t)(tn + h * 64 + srow) * K + (size_t)tc * 64 + sl * 8;
    async_load16(src, dst);
    async_load16(src + (size_t)32 * K, dst + 4096);
  };
  auto ldA = [&](int buf, int mh) {
    const char* base = lds + buf * 16384;
#pragma unroll
    for (int f = 0; f < 2; ++f) {
      const int R = wr * 64 + (mh * 2 + f) * 16 + l15;
#pragma unroll
      for (int kk = 0; kk < 2; ++kk)
        am[f][kk] = *(const bf16x8*)(base + R * 128 + (((kk * 4 + q4) ^ (R & 7)) * 16));
    }
  };
  auto ldB = [&](int buf) {
    const char* base = lds + 32768 + buf * 16384;
#pragma unroll
    for (int f = 0; f < 4; ++f) {
      const int R = wc * 64 + f * 16 + l15;
#pragma unroll
      for (int kk = 0; kk < 2; ++kk)
        bv[f][kk] = *(const bf16x8*)(base + R * 128 + (((kk * 4 + q4) ^ (R & 7)) * 16));
    }
  };

#define MMA_QUAD(MH, NH)                                                        \
  do {                                                                          \
    __builtin_amdgcn_s_setprio(1);                                              \
    _Pragma("unroll") for (int f = 0; f < 2; ++f)                               \
      _Pragma("unroll") for (int g = 0; g < 2; ++g)                             \
        _Pragma("unroll") for (int kk = 0; kk < 2; ++kk)                        \
          acc[(MH)*2+f][(NH)*2+g] =                                             \
              MFMA16(am[f][kk], bv[(NH)*2+g][kk], acc[(MH)*2+f][(NH)*2+g],0,0,0);\
    __builtin_amdgcn_s_setprio(0);                                              \
  } while (0)

  // prologue: T0 {B0,B1,A0,A1}, T1 {B0,B1,A0}; vmcnt(6) lands exactly T0; barrier.
  stageB(0, 0); stageB(0, 1); stageA(0, 0); stageA(0, 1);
  stageB(1, 0); stageB(1, 1); stageA(1, 0);
  vm6(); bar();

  const int iters = kt >> 1;
  for (int i = 0; i < iters; ++i) {
    const int t3 = 2 * i + 1, ta = 2 * i + 2, tb = 2 * i + 3;
    // ph1: read tile 2i (buf0) A-m0 + all B; stage A1(t3)
    ldA(0, 0); ldB(0); stageA(t3, 1);
    bar(); MMA_QUAD(0, 0); bar();
    // ph2: stage B0(ta)
    stageB(ta, 0);
    bar(); MMA_QUAD(0, 1); bar();
    // ph3: read A-m1; stage B1(ta)
    ldA(0, 1); stageB(ta, 1);
    bar(); MMA_QUAD(1, 1); bar();
    // ph4: stage A0(ta); counted wait
    stageA(ta, 0);
    bar(); MMA_QUAD(1, 0); vm6(); bar();
    // ph5: read tile 2i+1 (buf1); stage A1(ta)
    ldA(1, 0); ldB(1); stageA(ta, 1);
    bar(); MMA_QUAD(0, 0); bar();
    // ph6: stage B0(tb)
    stageB(tb, 0);
    bar(); MMA_QUAD(0, 1); bar();
    // ph7: read A-m1; stage B1(tb)
    ldA(1, 1); stageB(tb, 1);
    bar(); MMA_QUAD(1, 1); bar();
    // ph8: stage A0(tb); counted wait
    stageA(tb, 0);
    bar(); MMA_QUAD(1, 0); vm6(); bar();
  }
#undef MMA_QUAD

  const int cn = lane & 15, cr4 = (lane >> 4) * 4;
#pragma unroll
  for (int im = 0; im < 4; ++im) {
#pragma unroll
    for (int in_ = 0; in_ < 4; ++in_) {
      const int col = tn + wc * 64 + in_ * 16 + cn;
      const float bvv = bias[col];
#pragma unroll
      for (int j = 0; j < 4; ++j) {
        const int row = tm + wr * 64 + im * 16 + cr4 + j;
        if (row < M) {
          const float v = acc[im][in_][j] + bvv;
          if (EPI == 0) {
            ((u16*)Cout)[(size_t)row * ldc + col] = f2bf(gelu_fast(v));
          } else {
            const int b = row / 197, pp = row % 197;
            ((float*)Cout)[((size_t)(b * 203 + 6 + pp)) * 768 + col] = v;
          }
        }
      }
    }
  }
}

// ---------------- candidate GEMM: per (n,r,row-half) 32x128 tile (round-7 proven) ----------------
__global__ __launch_bounds__(256, 4) void cand_gemm(
    const u16* __restrict__ hid, const u16* __restrict__ wao,
    const float* __restrict__ bout, const int* __restrict__ rstar,
    const float* __restrict__ wstar, float* __restrict__ out) {
  __shared__ u16 As[2][32 * 64];
  __shared__ u16 Bs[2][128 * 64];
  const int g = blockIdx.y, n = g >> 1, r = g & 1;
  const int src_a = (r == 0) ? (n >> 1) : (3 + (n & 1));
  const int dst_a = (r == 1) ? (n >> 1) : (3 + (n & 1));
  const int tn = blockIdx.x * 128;
  const int b0 = blockIdx.z * 32;
  const int tid = threadIdx.x, lane = tid & 63, wid = tid >> 6;
  const u16* Bbase = wao + (size_t)dst_a * 768 * 3072;
  const u16* Abase = hid + (size_t)src_a * 3072 + (size_t)n * 15360;

  f32x4 acc[2][2] = {};

  auto stage = [&](int buf, int t) {
    const int k0 = t << 6;
    {
      const int row = tid >> 3;
      const int slA = (tid & 7) ^ (row & 7);
      async_load16(Abase + (size_t)(b0 + row) * 6 * 15360 + k0 + slA * 8,
                   (char*)As[buf] + row * 128 + (tid & 7) * 16);
    }
#pragma unroll
    for (int j = 0; j < 4; ++j) {
      const int row = j * 32 + (tid >> 3);
      const int slB = (tid & 7) ^ (row & 7);
      async_load16(Bbase + (size_t)(tn + row) * 3072 + k0 + slB * 8,
                   (char*)Bs[buf] + row * 128 + (tid & 7) * 16);
    }
  };
  auto compute = [&](int buf) {
    const u16* as = As[buf];
    const u16* bs = Bs[buf];
#pragma unroll
    for (int kk = 0; kk < 2; ++kk) {
      bf16x8 af[2], bfv[2];
#pragma unroll
      for (int im = 0; im < 2; ++im) {
        const int R = im * 16 + (lane & 15);
        const int s = (kk * 4 + (lane >> 4)) ^ (R & 7);
        af[im] = *(const bf16x8*)(as + R * 64 + s * 8);
      }
#pragma unroll
      for (int q = 0; q < 2; ++q) {
        const int R = wid * 32 + q * 16 + (lane & 15);
        const int s = (kk * 4 + (lane >> 4)) ^ (R & 7);
        bfv[q] = *(const bf16x8*)(bs + R * 64 + s * 8);
      }
#pragma unroll
      for (int im = 0; im < 2; ++im)
#pragma unroll
        for (int q = 0; q < 2; ++q)
          acc[im][q] = MFMA16(af[im], bfv[q], acc[im][q], 0, 0, 0);
    }
  };

  stage(0, 0);
  __syncthreads();
  for (int t = 0; t < 48; ++t) {
    if (t + 1 < 48) stage((t + 1) & 1, t + 1);
    compute(t & 1);
    __syncthreads();
  }

  const int cn = lane & 15, cr4 = (lane >> 4) * 4;
#pragma unroll
  for (int im = 0; im < 2; ++im)
#pragma unroll
    for (int q = 0; q < 2; ++q) {
      const int col = tn + wid * 32 + q * 16 + cn;
      const float bvv = bout[dst_a * 768 + col];
#pragma unroll
      for (int j = 0; j < 4; ++j) {
        const int b = b0 + im * 16 + cr4 + j;
        const int idx = b * 6 + n;
        if (rstar[idx] == r)
          out[((size_t)(b * 203 + n)) * 768 + col] = (acc[im][q][j] + bvv) * wstar[idx];
      }
    }
}

// ---------------- launch ----------------
extern "C" void kernel_launch(void* const* d_in, const int* in_sizes, int n_in,
                              void* d_out, int out_size, void* d_ws, size_t ws_size,
                              hipStream_t stream) {
  const float* x     = (const float*)d_in[0];
  const float* fc1w  = (const float*)d_in[1];
  const float* fc1b  = (const float*)d_in[2];
  const float* fc2w  = (const float*)d_in[3];
  const float* fc2b  = (const float*)d_in[4];
  const float* gpair = (const float*)d_in[5];
  const float* aiw   = (const float*)d_in[6];
  const float* aib   = (const float*)d_in[7];
  const float* aow   = (const float*)d_in[8];
  const float* aob   = (const float*)d_in[9];
  const float* bbias = (const float*)d_in[10];
  float* out = (float*)d_out;

  char* ws = (char*)d_ws;
  u16* xp   = (u16*)(ws + 0);          // 12608x768 bf16
  u16* xc   = (u16*)(ws + 19365888);   // 384x768
  u16* w1   = (u16*)(ws + 19955712);   // 3072x768
  u16* w2   = (u16*)(ws + 24674304);   // 768x3072
  u16* wai  = (u16*)(ws + 29392896);   // 5x3072x768
  u16* wao  = (u16*)(ws + 52985856);   // 5x768x3072
  u16* hb   = (u16*)(ws + 76578816);   // 12608x3072
  u16* hid  = (u16*)(ws + 154042368);  // 384x15360
  int*   rstar = (int*)(ws + 165838848);
  float* wstar = (float*)(ws + 165840384);
  if (ws_size < 165841920) return;

  cvt_x2<<<dim3(203, 64), 192, 0, stream>>>(x, xc, xp);
  cvt_w<<<27648, 256, 0, stream>>>(fc1w, w1, fc2w, w2, aiw, wai, aow, wao);
  gate_kernel<<<96, 256, 0, stream>>>(x, gpair, bbias, rstar, wstar);
  // patch fc1 + gelu -> hb (bf16)
  gemm8p<0><<<dim3(24, 99), 256, 0, stream>>>(xp, w1, fc1b, hb, 12608, 768, 3072);
  // hid_all = gelu(cls @ atom_in_w^T + b) for all 5 atoms
  gemm8p<0><<<dim3(120, 3), 256, 0, stream>>>(xc, wai, aib, hid, 384, 768, 15360);
  // patch fc2 -> d_out (scatter to b*203+6+p rows)
  gemm8p<1><<<dim3(6, 99), 256, 0, stream>>>(hb, w2, fc2b, out, 12608, 3072, 768);
  // route candidates, chosen one written * prob
  cand_gemm<<<dim3(6, 12, 2), 256, 0, stream>>>(hid, wao, aob, rstar, wstar, out);
}

// Round 11
// 257.062 us; speedup vs baseline: 2.5539x; 1.4123x over previous
//
#include <hip/hip_runtime.h>
#include <hip/hip_bf16.h>

// Mlp_moe: patch MLP + 6-class 2-route MoE on cls tokens.
// Round 11: best-measured bodies locked (round-1 gemm, round-7 cand); launches fused to 3
// dispatches so under-filled grids overlap: [cvt+gate] -> [fc1+hid] -> [fc2+cand].

typedef __bf16 bf16x8 __attribute__((ext_vector_type(8)));
typedef float f32x4 __attribute__((ext_vector_type(4)));
typedef unsigned short u16;

#define DEVINL __device__ __forceinline__

DEVINL u16 f2bf(float f) {
  unsigned int u = __builtin_bit_cast(unsigned int, f);
  u += 0x7FFFu + ((u >> 16) & 1u);
  return (u16)(u >> 16);
}

// Winitzki erf: abs err ~2e-4 (vs bf16 rounding 0.008), branch-free.
DEVINL float gelu_fast(float v) {
  const float x2 = 0.5f * v * v;
  const float t = x2 * (1.27323954f + 0.147f * x2) / (1.0f + 0.147f * x2);
  const float r = sqrtf(fmaxf(1.0f - __expf(-t), 0.0f));
  const float e = copysignf(r, v);
  return 0.5f * v * (1.0f + e);
}

DEVINL void async_load16(const void* g, void* l) {
  __builtin_amdgcn_global_load_lds(
      (const __attribute__((address_space(1))) unsigned int*)g,
      (__attribute__((address_space(3))) unsigned int*)l, 16, 0, 0);
}

#define MFMA16 __builtin_amdgcn_mfma_f32_16x16x32_bf16

// ---------------- fused conversions + gate (one dispatch) ----------------
// blocks [0,9744): x split; [9744,37392): 4 weight regions; [37392,37488): gate.
__global__ void cvt_gate(const float* __restrict__ x, u16* __restrict__ xc, u16* __restrict__ xp,
                         const float* __restrict__ s1, u16* __restrict__ d1,
                         const float* __restrict__ s2, u16* __restrict__ d2,
                         const float* __restrict__ s3, u16* __restrict__ d3,
                         const float* __restrict__ s4, u16* __restrict__ d4,
                         const float* __restrict__ gate_pair,
                         const float* __restrict__ balance_bias,
                         int* __restrict__ rstar, float* __restrict__ wstar) {
  int b = blockIdx.x;
  if (b < 9744) {
    const int e = (b * 256 + threadIdx.x) * 4;
    const int t = e / 768, dd = e % 768;
    const int bb = t / 203, i = t % 203;
    const float4 v = *(const float4*)(x + e);
    ushort4 u;
    u.x = f2bf(v.x); u.y = f2bf(v.y); u.z = f2bf(v.z); u.w = f2bf(v.w);
    if (i < 6) *(ushort4*)(xc + (size_t)(bb * 6 + i) * 768 + dd) = u;
    else       *(ushort4*)(xp + (size_t)(bb * 197 + (i - 6)) * 768 + dd) = u;
    return;
  }
  b -= 9744;
  if (b < 27648) {
    const float* s; u16* d;
    if (b < 2304) { s = s1; d = d1; }
    else if (b < 4608) { s = s2; d = d2; b -= 2304; }
    else if (b < 16128) { s = s3; d = d3; b -= 4608; }
    else { s = s4; d = d4; b -= 16128; }
    const int i = (b * 256 + threadIdx.x) * 4;
    const float4 v = *(const float4*)(s + i);
    ushort4 u;
    u.x = f2bf(v.x); u.y = f2bf(v.y); u.z = f2bf(v.z); u.w = f2bf(v.w);
    *(ushort4*)(d + i) = u;
    return;
  }
  b -= 27648;  // gate: 96 blocks x 4 waves
  const int lane = threadIdx.x & 63, wid = threadIdx.x >> 6;
  const int idx = b * 4 + wid;
  const int bb = idx / 6, n = idx % 6;
  const float* xv = x + (size_t)(bb * 203 + n) * 768;
  const float* w0 = gate_pair + (size_t)(n * 2 + 0) * 768;
  const float* w1 = gate_pair + (size_t)(n * 2 + 1) * 768;
  double xx = 0, a00 = 0, a11 = 0, p0 = 0, p1 = 0;
  for (int d = lane; d < 768; d += 64) {
    double xd = xv[d], g0 = w0[d], g1 = w1[d];
    xx += xd * xd; a00 += g0 * g0; a11 += g1 * g1; p0 += xd * g0; p1 += xd * g1;
  }
#pragma unroll
  for (int off = 32; off; off >>= 1) {
    xx  += __shfl_xor(xx, off);
    a00 += __shfl_xor(a00, off);
    a11 += __shfl_xor(a11, off);
    p0  += __shfl_xor(p0, off);
    p1  += __shfl_xor(p1, off);
  }
  if (lane == 0) {
    double nx = fmax(sqrt(xx), 1e-12), n0 = fmax(sqrt(a00), 1e-12), n1 = fmax(sqrt(a11), 1e-12);
    double l0 = p0 / (nx * n0) + (double)balance_bias[n * 2 + 0];
    double l1 = p1 / (nx * n1) + (double)balance_bias[n * 2 + 1];
    const int r = (l1 > l0) ? 1 : 0;
    double m = fmax(l0, l1);
    double e0 = exp(l0 - m), e1 = exp(l1 - m);
    rstar[idx] = r;
    wstar[idx] = (float)(((r == 1) ? e1 : e0) / (e0 + e1));
  }
}

// ---------------- round-1 gemm body (best measured: 100.6us, MfmaUtil 25, occ 35) ----------------
template <int EPI>
DEVINL void gemm_body(const u16* __restrict__ A, const u16* __restrict__ B,
                      const float* __restrict__ bias, void* __restrict__ Cout,
                      int M, int K, int ldc, int bx, int by, u16* As, u16* Bs) {
  const int tid = threadIdx.x;
  const int lane = tid & 63, wid = tid >> 6;
  const int wr = wid >> 1, wc = wid & 1;
  const int tm = by * 128, tn = bx * 128;
  const int rA = lane >> 3, sA = lane & 7;
  const int ksteps = K >> 6;

  f32x4 acc[4][4] = {};

  for (int ks = 0; ks < ksteps; ++ks) {
    const int k0 = ks << 6;
#pragma unroll
    for (int c = 0; c < 4; ++c) {
      const int chunk = wid * 4 + c;
      const int row   = chunk * 8 + rA;
      int grow = tm + row;
      grow = grow < M ? grow : (M - 1);  // clamp tail rows (never stored)
      const int slot = sA ^ (row & 7);
      async_load16(A + (size_t)grow * K + k0 + slot * 8, (char*)As + chunk * 1024);
    }
#pragma unroll
    for (int c = 0; c < 4; ++c) {
      const int chunk = wid * 4 + c;
      const int row   = chunk * 8 + rA;
      const int slot  = sA ^ (row & 7);
      async_load16(B + (size_t)(tn + row) * K + k0 + slot * 8, (char*)Bs + chunk * 1024);
    }
    __syncthreads();  // vmcnt(0) drain: staged data visible
#pragma unroll
    for (int kk = 0; kk < 2; ++kk) {
      bf16x8 af[4], bfv[4];
#pragma unroll
      for (int im = 0; im < 4; ++im) {
        const int R = wr * 64 + im * 16 + (lane & 15);
        const int s = (kk * 4 + (lane >> 4)) ^ (R & 7);
        af[im] = *(const bf16x8*)((const char*)As + R * 128 + s * 16);
      }
#pragma unroll
      for (int in_ = 0; in_ < 4; ++in_) {
        const int R = wc * 64 + in_ * 16 + (lane & 15);
        const int s = (kk * 4 + (lane >> 4)) ^ (R & 7);
        bfv[in_] = *(const bf16x8*)((const char*)Bs + R * 128 + s * 16);
      }
#pragma unroll
      for (int im = 0; im < 4; ++im)
#pragma unroll
        for (int in_ = 0; in_ < 4; ++in_)
          acc[im][in_] = MFMA16(af[im], bfv[in_], acc[im][in_], 0, 0, 0);
    }
    __syncthreads();  // protect single buffer
  }

  const int cn = lane & 15, cr4 = (lane >> 4) * 4;
#pragma unroll
  for (int im = 0; im < 4; ++im) {
#pragma unroll
    for (int in_ = 0; in_ < 4; ++in_) {
      const int col = tn + wc * 64 + in_ * 16 + cn;
      const float bv = bias[col];
#pragma unroll
      for (int j = 0; j < 4; ++j) {
        const int row = tm + wr * 64 + im * 16 + cr4 + j;
        if (row < M) {
          const float v = acc[im][in_][j] + bv;
          if (EPI == 0) {
            ((u16*)Cout)[(size_t)row * ldc + col] = f2bf(gelu_fast(v));
          } else {
            const int b = row / 197, pp = row % 197;
            ((float*)Cout)[((size_t)(b * 203 + 6 + pp)) * 768 + col] = v;
          }
        }
      }
    }
  }
}

// ---------------- round-7 cand body (32x128 tile, dbuf 2-phase) ----------------
DEVINL void cand_body(const u16* __restrict__ hid, const u16* __restrict__ wao,
                      const float* __restrict__ bout, const int* __restrict__ rstar,
                      const float* __restrict__ wstar, float* __restrict__ out,
                      int bx, int g, int bz, char* smem) {
  // smem layout: As[2] @ 0 (2x4KB), Bs[2] @ 8192 (2x16KB) -> 40KB total
  const int n = g >> 1, r = g & 1;
  const int src_a = (r == 0) ? (n >> 1) : (3 + (n & 1));   // src[n] = {n/2, 3+(n&1)}
  const int dst_a = (r == 1) ? (n >> 1) : (3 + (n & 1));   // dst[n][r] = src[n][1-r]
  const int tn = bx * 128;
  const int b0 = bz * 32;
  const int tid = threadIdx.x, lane = tid & 63, wid = tid >> 6;
  const u16* Bbase = wao + (size_t)dst_a * 768 * 3072;
  const u16* Abase = hid + (size_t)src_a * 3072 + (size_t)n * 15360;

  f32x4 acc[2][2] = {};

  auto stage = [&](int buf, int t) {
    const int k0 = t << 6;
    {
      const int row = tid >> 3;  // 0..31
      const int slA = (tid & 7) ^ (row & 7);
      async_load16(Abase + (size_t)(b0 + row) * 6 * 15360 + k0 + slA * 8,
                   smem + buf * 4096 + row * 128 + (tid & 7) * 16);
    }
#pragma unroll
    for (int j = 0; j < 4; ++j) {
      const int row = j * 32 + (tid >> 3);  // 0..127
      const int slB = (tid & 7) ^ (row & 7);
      async_load16(Bbase + (size_t)(tn + row) * 3072 + k0 + slB * 8,
                   smem + 8192 + buf * 16384 + row * 128 + (tid & 7) * 16);
    }
  };
  auto compute = [&](int buf) {
    const u16* as = (const u16*)(smem + buf * 4096);
    const u16* bs = (const u16*)(smem + 8192 + buf * 16384);
#pragma unroll
    for (int kk = 0; kk < 2; ++kk) {
      bf16x8 af[2], bfv[2];
#pragma unroll
      for (int im = 0; im < 2; ++im) {
        const int R = im * 16 + (lane & 15);
        const int s = (kk * 4 + (lane >> 4)) ^ (R & 7);
        af[im] = *(const bf16x8*)(as + R * 64 + s * 8);
      }
#pragma unroll
      for (int q = 0; q < 2; ++q) {
        const int R = wid * 32 + q * 16 + (lane & 15);
        const int s = (kk * 4 + (lane >> 4)) ^ (R & 7);
        bfv[q] = *(const bf16x8*)(bs + R * 64 + s * 8);
      }
#pragma unroll
      for (int im = 0; im < 2; ++im)
#pragma unroll
        for (int q = 0; q < 2; ++q)
          acc[im][q] = MFMA16(af[im], bfv[q], acc[im][q], 0, 0, 0);
    }
  };

  stage(0, 0);
  __syncthreads();
  for (int t = 0; t < 48; ++t) {
    if (t + 1 < 48) stage((t + 1) & 1, t + 1);
    compute(t & 1);
    __syncthreads();
  }

  const int cn = lane & 15, cr4 = (lane >> 4) * 4;
#pragma unroll
  for (int im = 0; im < 2; ++im)
#pragma unroll
    for (int q = 0; q < 2; ++q) {
      const int col = tn + wid * 32 + q * 16 + cn;
      const float bv = bout[dst_a * 768 + col];
#pragma unroll
      for (int j = 0; j < 4; ++j) {
        const int b = b0 + im * 16 + cr4 + j;
        const int idx = b * 6 + n;
        if (rstar[idx] == r)
          out[((size_t)(b * 203 + n)) * 768 + col] = (acc[im][q][j] + bv) * wstar[idx];
      }
    }
}

// ---------------- fused dispatch 2: fc1 (2376 blocks) + hid_all (360 blocks) ----------------
__global__ __launch_bounds__(256, 2) void gemm_f1(
    const u16* __restrict__ xp, const u16* __restrict__ w1, const float* __restrict__ fc1b,
    u16* __restrict__ hb,
    const u16* __restrict__ xc, const u16* __restrict__ wai, const float* __restrict__ aib,
    u16* __restrict__ hidb) {
  __shared__ u16 As[128 * 64];
  __shared__ u16 Bs[128 * 64];
  int id = blockIdx.x;
  if (id < 2376) {
    gemm_body<0>(xp, w1, fc1b, hb, 12608, 768, 3072, id % 24, id / 24, As, Bs);
  } else {
    id -= 2376;
    gemm_body<0>(xc, wai, aib, hidb, 384, 768, 15360, id % 120, id / 120, As, Bs);
  }
}

// ---------------- fused dispatch 3: fc2 (594 blocks) + cand (144 blocks) ----------------
// 738 blocks <= resident capacity -> cand rides free inside fc2's dispatch.
__global__ __launch_bounds__(256, 2) void gemm_f2(
    const u16* __restrict__ hb, const u16* __restrict__ w2, const float* __restrict__ fc2b,
    float* __restrict__ out,
    const u16* __restrict__ hidb, const u16* __restrict__ wao, const float* __restrict__ aob,
    const int* __restrict__ rstar, const float* __restrict__ wstar) {
  __shared__ char smem[40960];
  int id = blockIdx.x;
  if (id < 594) {
    gemm_body<1>(hb, w2, fc2b, out, 12608, 3072, 768, id % 6, id / 6,
                 (u16*)smem, (u16*)(smem + 16384));
  } else {
    id -= 594;
    cand_body(hidb, wao, aob, rstar, wstar, out, id % 6, (id / 6) % 12, id / 72, smem);
  }
}

// ---------------- launch ----------------
extern "C" void kernel_launch(void* const* d_in, const int* in_sizes, int n_in,
                              void* d_out, int out_size, void* d_ws, size_t ws_size,
                              hipStream_t stream) {
  const float* x     = (const float*)d_in[0];
  const float* fc1w  = (const float*)d_in[1];
  const float* fc1b  = (const float*)d_in[2];
  const float* fc2w  = (const float*)d_in[3];
  const float* fc2b  = (const float*)d_in[4];
  const float* gpair = (const float*)d_in[5];
  const float* aiw   = (const float*)d_in[6];
  const float* aib   = (const float*)d_in[7];
  const float* aow   = (const float*)d_in[8];
  const float* aob   = (const float*)d_in[9];
  const float* bbias = (const float*)d_in[10];
  float* out = (float*)d_out;

  char* ws = (char*)d_ws;
  u16* xp   = (u16*)(ws + 0);          // 12608x768 bf16
  u16* xc   = (u16*)(ws + 19365888);   // 384x768
  u16* w1   = (u16*)(ws + 19955712);   // 3072x768
  u16* w2   = (u16*)(ws + 24674304);   // 768x3072
  u16* wai  = (u16*)(ws + 29392896);   // 5x3072x768
  u16* wao  = (u16*)(ws + 52985856);   // 5x768x3072
  u16* hb   = (u16*)(ws + 76578816);   // 12608x3072
  u16* hid  = (u16*)(ws + 154042368);  // 384x15360
  int*   rstar = (int*)(ws + 165838848);
  float* wstar = (float*)(ws + 165840384);
  if (ws_size < 165841920) return;

  // dispatch 1: all conversions + gate (9744 + 27648 + 96 blocks)
  cvt_gate<<<37488, 256, 0, stream>>>(x, xc, xp, fc1w, w1, fc2w, w2, aiw, wai, aow, wao,
                                      gpair, bbias, rstar, wstar);
  // dispatch 2: fc1 + hid_all
  gemm_f1<<<2736, 256, 0, stream>>>(xp, w1, fc1b, hb, xc, wai, aib, hid);
  // dispatch 3: fc2 + route candidates
  gemm_f2<<<738, 256, 0, stream>>>(hb, w2, fc2b, out, hid, wao, aob, rstar, wstar);
}

// Round 12
// 234.280 us; speedup vs baseline: 2.8022x; 1.0972x over previous
//
#include <hip/hip_runtime.h>
#include <hip/hip_bf16.h>

// Mlp_moe: patch MLP + 6-class 2-route MoE on cls tokens.
// Round 12: round-11 structure locked (3 fused dispatches). Micro bundle:
// T1 XCD-chunked swizzle on fc1/fc2 tile ids; native bf16 casts (enable v_cvt_pk);
// incremental div-197 in fc2 scatter epilogue.

typedef __bf16 bf16x8 __attribute__((ext_vector_type(8)));
typedef float f32x4 __attribute__((ext_vector_type(4)));
typedef unsigned short u16;

#define DEVINL __device__ __forceinline__

DEVINL u16 f2bf(float f) {  // native cast: RNE, compiler may pack as v_cvt_pk_bf16_f32
  __bf16 h = (__bf16)f;
  return __builtin_bit_cast(u16, h);
}

// Winitzki erf: abs err ~2e-4 (vs bf16 rounding 0.008), branch-free.
DEVINL float gelu_fast(float v) {
  const float x2 = 0.5f * v * v;
  const float t = x2 * (1.27323954f + 0.147f * x2) / (1.0f + 0.147f * x2);
  const float r = sqrtf(fmaxf(1.0f - __expf(-t), 0.0f));
  const float e = copysignf(r, v);
  return 0.5f * v * (1.0f + e);
}

DEVINL void async_load16(const void* g, void* l) {
  __builtin_amdgcn_global_load_lds(
      (const __attribute__((address_space(1))) unsigned int*)g,
      (__attribute__((address_space(3))) unsigned int*)l, 16, 0, 0);
}

#define MFMA16 __builtin_amdgcn_mfma_f32_16x16x32_bf16

// ---------------- fused conversions + gate (one dispatch) ----------------
__global__ void cvt_gate(const float* __restrict__ x, u16* __restrict__ xc, u16* __restrict__ xp,
                         const float* __restrict__ s1, u16* __restrict__ d1,
                         const float* __restrict__ s2, u16* __restrict__ d2,
                         const float* __restrict__ s3, u16* __restrict__ d3,
                         const float* __restrict__ s4, u16* __restrict__ d4,
                         const float* __restrict__ gate_pair,
                         const float* __restrict__ balance_bias,
                         int* __restrict__ rstar, float* __restrict__ wstar) {
  int b = blockIdx.x;
  if (b < 9744) {
    const int e = (b * 256 + threadIdx.x) * 4;
    const int t = e / 768, dd = e % 768;
    const int bb = t / 203, i = t % 203;
    const float4 v = *(const float4*)(x + e);
    ushort4 u;
    u.x = f2bf(v.x); u.y = f2bf(v.y); u.z = f2bf(v.z); u.w = f2bf(v.w);
    if (i < 6) *(ushort4*)(xc + (size_t)(bb * 6 + i) * 768 + dd) = u;
    else       *(ushort4*)(xp + (size_t)(bb * 197 + (i - 6)) * 768 + dd) = u;
    return;
  }
  b -= 9744;
  if (b < 27648) {
    const float* s; u16* d;
    if (b < 2304) { s = s1; d = d1; }
    else if (b < 4608) { s = s2; d = d2; b -= 2304; }
    else if (b < 16128) { s = s3; d = d3; b -= 4608; }
    else { s = s4; d = d4; b -= 16128; }
    const int i = (b * 256 + threadIdx.x) * 4;
    const float4 v = *(const float4*)(s + i);
    ushort4 u;
    u.x = f2bf(v.x); u.y = f2bf(v.y); u.z = f2bf(v.z); u.w = f2bf(v.w);
    *(ushort4*)(d + i) = u;
    return;
  }
  b -= 27648;  // gate: 96 blocks x 4 waves
  const int lane = threadIdx.x & 63, wid = threadIdx.x >> 6;
  const int idx = b * 4 + wid;
  const int bb = idx / 6, n = idx % 6;
  const float* xv = x + (size_t)(bb * 203 + n) * 768;
  const float* w0 = gate_pair + (size_t)(n * 2 + 0) * 768;
  const float* w1 = gate_pair + (size_t)(n * 2 + 1) * 768;
  double xx = 0, a00 = 0, a11 = 0, p0 = 0, p1 = 0;
  for (int d = lane; d < 768; d += 64) {
    double xd = xv[d], g0 = w0[d], g1 = w1[d];
    xx += xd * xd; a00 += g0 * g0; a11 += g1 * g1; p0 += xd * g0; p1 += xd * g1;
  }
#pragma unroll
  for (int off = 32; off; off >>= 1) {
    xx  += __shfl_xor(xx, off);
    a00 += __shfl_xor(a00, off);
    a11 += __shfl_xor(a11, off);
    p0  += __shfl_xor(p0, off);
    p1  += __shfl_xor(p1, off);
  }
  if (lane == 0) {
    double nx = fmax(sqrt(xx), 1e-12), n0 = fmax(sqrt(a00), 1e-12), n1 = fmax(sqrt(a11), 1e-12);
    double l0 = p0 / (nx * n0) + (double)balance_bias[n * 2 + 0];
    double l1 = p1 / (nx * n1) + (double)balance_bias[n * 2 + 1];
    const int r = (l1 > l0) ? 1 : 0;
    double m = fmax(l0, l1);
    double e0 = exp(l0 - m), e1 = exp(l1 - m);
    rstar[idx] = r;
    wstar[idx] = (float)(((r == 1) ? e1 : e0) / (e0 + e1));
  }
}

// ---------------- round-1 gemm body (best measured) ----------------
template <int EPI>
DEVINL void gemm_body(const u16* __restrict__ A, const u16* __restrict__ B,
                      const float* __restrict__ bias, void* __restrict__ Cout,
                      int M, int K, int ldc, int bx, int by, u16* As, u16* Bs) {
  const int tid = threadIdx.x;
  const int lane = tid & 63, wid = tid >> 6;
  const int wr = wid >> 1, wc = wid & 1;
  const int tm = by * 128, tn = bx * 128;
  const int rA = lane >> 3, sA = lane & 7;
  const int ksteps = K >> 6;

  f32x4 acc[4][4] = {};

  for (int ks = 0; ks < ksteps; ++ks) {
    const int k0 = ks << 6;
#pragma unroll
    for (int c = 0; c < 4; ++c) {
      const int chunk = wid * 4 + c;
      const int row   = chunk * 8 + rA;
      int grow = tm + row;
      grow = grow < M ? grow : (M - 1);  // clamp tail rows (never stored)
      const int slot = sA ^ (row & 7);
      async_load16(A + (size_t)grow * K + k0 + slot * 8, (char*)As + chunk * 1024);
    }
#pragma unroll
    for (int c = 0; c < 4; ++c) {
      const int chunk = wid * 4 + c;
      const int row   = chunk * 8 + rA;
      const int slot  = sA ^ (row & 7);
      async_load16(B + (size_t)(tn + row) * K + k0 + slot * 8, (char*)Bs + chunk * 1024);
    }
    __syncthreads();  // vmcnt(0) drain: staged data visible
#pragma unroll
    for (int kk = 0; kk < 2; ++kk) {
      bf16x8 af[4], bfv[4];
#pragma unroll
      for (int im = 0; im < 4; ++im) {
        const int R = wr * 64 + im * 16 + (lane & 15);
        const int s = (kk * 4 + (lane >> 4)) ^ (R & 7);
        af[im] = *(const bf16x8*)((const char*)As + R * 128 + s * 16);
      }
#pragma unroll
      for (int in_ = 0; in_ < 4; ++in_) {
        const int R = wc * 64 + in_ * 16 + (lane & 15);
        const int s = (kk * 4 + (lane >> 4)) ^ (R & 7);
        bfv[in_] = *(const bf16x8*)((const char*)Bs + R * 128 + s * 16);
      }
#pragma unroll
      for (int im = 0; im < 4; ++im)
#pragma unroll
        for (int in_ = 0; in_ < 4; ++in_)
          acc[im][in_] = MFMA16(af[im], bfv[in_], acc[im][in_], 0, 0, 0);
    }
    __syncthreads();  // protect single buffer
  }

  const int cn = lane & 15, cr4 = (lane >> 4) * 4;
  const int col0 = tn + wc * 64 + cn;
  const int r0 = tm + wr * 64;
  // EPI==1: incremental div-197 (offsets < 197 -> single wrap)
  int b197 = 0, p197 = 0;
  if (EPI == 1) { b197 = r0 / 197; p197 = r0 % 197; }
#pragma unroll
  for (int im = 0; im < 4; ++im) {
#pragma unroll
    for (int in_ = 0; in_ < 4; ++in_) {
      const int col = col0 + in_ * 16;
      const float bv = bias[col];
#pragma unroll
      for (int j = 0; j < 4; ++j) {
        const int off = im * 16 + cr4 + j;
        const int row = r0 + off;
        if (row < M) {
          const float v = acc[im][in_][j] + bv;
          if (EPI == 0) {
            ((u16*)Cout)[(size_t)row * ldc + col] = f2bf(gelu_fast(v));
          } else {
            int pp = p197 + off, bb = b197;
            if (pp >= 197) { pp -= 197; ++bb; }
            ((float*)Cout)[((size_t)(bb * 203 + 6 + pp)) * 768 + col] = v;
          }
        }
      }
    }
  }
}

// ---------------- round-7 cand body (32x128 tile, dbuf 2-phase) ----------------
DEVINL void cand_body(const u16* __restrict__ hid, const u16* __restrict__ wao,
                      const float* __restrict__ bout, const int* __restrict__ rstar,
                      const float* __restrict__ wstar, float* __restrict__ out,
                      int bx, int g, int bz, char* smem) {
  const int n = g >> 1, r = g & 1;
  const int src_a = (r == 0) ? (n >> 1) : (3 + (n & 1));
  const int dst_a = (r == 1) ? (n >> 1) : (3 + (n & 1));
  const int tn = bx * 128;
  const int b0 = bz * 32;
  const int tid = threadIdx.x, lane = tid & 63, wid = tid >> 6;
  const u16* Bbase = wao + (size_t)dst_a * 768 * 3072;
  const u16* Abase = hid + (size_t)src_a * 3072 + (size_t)n * 15360;

  f32x4 acc[2][2] = {};

  auto stage = [&](int buf, int t) {
    const int k0 = t << 6;
    {
      const int row = tid >> 3;
      const int slA = (tid & 7) ^ (row & 7);
      async_load16(Abase + (size_t)(b0 + row) * 6 * 15360 + k0 + slA * 8,
                   smem + buf * 4096 + row * 128 + (tid & 7) * 16);
    }
#pragma unroll
    for (int j = 0; j < 4; ++j) {
      const int row = j * 32 + (tid >> 3);
      const int slB = (tid & 7) ^ (row & 7);
      async_load16(Bbase + (size_t)(tn + row) * 3072 + k0 + slB * 8,
                   smem + 8192 + buf * 16384 + row * 128 + (tid & 7) * 16);
    }
  };
  auto compute = [&](int buf) {
    const u16* as = (const u16*)(smem + buf * 4096);
    const u16* bs = (const u16*)(smem + 8192 + buf * 16384);
#pragma unroll
    for (int kk = 0; kk < 2; ++kk) {
      bf16x8 af[2], bfv[2];
#pragma unroll
      for (int im = 0; im < 2; ++im) {
        const int R = im * 16 + (lane & 15);
        const int s = (kk * 4 + (lane >> 4)) ^ (R & 7);
        af[im] = *(const bf16x8*)(as + R * 64 + s * 8);
      }
#pragma unroll
      for (int q = 0; q < 2; ++q) {
        const int R = wid * 32 + q * 16 + (lane & 15);
        const int s = (kk * 4 + (lane >> 4)) ^ (R & 7);
        bfv[q] = *(const bf16x8*)(bs + R * 64 + s * 8);
      }
#pragma unroll
      for (int im = 0; im < 2; ++im)
#pragma unroll
        for (int q = 0; q < 2; ++q)
          acc[im][q] = MFMA16(af[im], bfv[q], acc[im][q], 0, 0, 0);
    }
  };

  stage(0, 0);
  __syncthreads();
  for (int t = 0; t < 48; ++t) {
    if (t + 1 < 48) stage((t + 1) & 1, t + 1);
    compute(t & 1);
    __syncthreads();
  }

  const int cn = lane & 15, cr4 = (lane >> 4) * 4;
#pragma unroll
  for (int im = 0; im < 2; ++im)
#pragma unroll
    for (int q = 0; q < 2; ++q) {
      const int col = tn + wid * 32 + q * 16 + cn;
      const float bv = bout[dst_a * 768 + col];
#pragma unroll
      for (int j = 0; j < 4; ++j) {
        const int b = b0 + im * 16 + cr4 + j;
        const int idx = b * 6 + n;
        if (rstar[idx] == r)
          out[((size_t)(b * 203 + n)) * 768 + col] = (acc[im][q][j] + bv) * wstar[idx];
      }
    }
}

// ---------------- fused dispatch 2: fc1 (2376, XCD-swizzled) + hid_all (360) ----------------
__global__ __launch_bounds__(256, 2) void gemm_f1(
    const u16* __restrict__ xp, const u16* __restrict__ w1, const float* __restrict__ fc1b,
    u16* __restrict__ hb,
    const u16* __restrict__ xc, const u16* __restrict__ wai, const float* __restrict__ aib,
    u16* __restrict__ hidb) {
  __shared__ u16 As[128 * 64];
  __shared__ u16 Bs[128 * 64];
  int id = blockIdx.x;
  if (id < 2376) {
    id = (id & 7) * 297 + (id >> 3);  // 2376 = 8*297, bijective XCD chunking
    gemm_body<0>(xp, w1, fc1b, hb, 12608, 768, 3072, id % 24, id / 24, As, Bs);
  } else {
    id -= 2376;
    gemm_body<0>(xc, wai, aib, hidb, 384, 768, 15360, id % 120, id / 120, As, Bs);
  }
}

// ---------------- fused dispatch 3: fc2 (594, XCD-swizzled) + cand (144) ----------------
__global__ __launch_bounds__(256, 2) void gemm_f2(
    const u16* __restrict__ hb, const u16* __restrict__ w2, const float* __restrict__ fc2b,
    float* __restrict__ out,
    const u16* __restrict__ hidb, const u16* __restrict__ wao, const float* __restrict__ aob,
    const int* __restrict__ rstar, const float* __restrict__ wstar) {
  __shared__ char smem[40960];
  int id = blockIdx.x;
  if (id < 594) {
    // m204 bijective chunking for nwg=594: q=74, r=2
    const int xcd = id & 7, k = id >> 3;
    id = (xcd < 2 ? xcd * 75 : 150 + (xcd - 2) * 74) + k;
    gemm_body<1>(hb, w2, fc2b, out, 12608, 3072, 768, id % 6, id / 6,
                 (u16*)smem, (u16*)(smem + 16384));
  } else {
    id -= 594;
    cand_body(hidb, wao, aob, rstar, wstar, out, id % 6, (id / 6) % 12, id / 72, smem);
  }
}

// ---------------- launch ----------------
extern "C" void kernel_launch(void* const* d_in, const int* in_sizes, int n_in,
                              void* d_out, int out_size, void* d_ws, size_t ws_size,
                              hipStream_t stream) {
  const float* x     = (const float*)d_in[0];
  const float* fc1w  = (const float*)d_in[1];
  const float* fc1b  = (const float*)d_in[2];
  const float* fc2w  = (const float*)d_in[3];
  const float* fc2b  = (const float*)d_in[4];
  const float* gpair = (const float*)d_in[5];
  const float* aiw   = (const float*)d_in[6];
  const float* aib   = (const float*)d_in[7];
  const float* aow   = (const float*)d_in[8];
  const float* aob   = (const float*)d_in[9];
  const float* bbias = (const float*)d_in[10];
  float* out = (float*)d_out;

  char* ws = (char*)d_ws;
  u16* xp   = (u16*)(ws + 0);          // 12608x768 bf16
  u16* xc   = (u16*)(ws + 19365888);   // 384x768
  u16* w1   = (u16*)(ws + 19955712);   // 3072x768
  u16* w2   = (u16*)(ws + 24674304);   // 768x3072
  u16* wai  = (u16*)(ws + 29392896);   // 5x3072x768
  u16* wao  = (u16*)(ws + 52985856);   // 5x768x3072
  u16* hb   = (u16*)(ws + 76578816);   // 12608x3072
  u16* hid  = (u16*)(ws + 154042368);  // 384x15360
  int*   rstar = (int*)(ws + 165838848);
  float* wstar = (float*)(ws + 165840384);
  if (ws_size < 165841920) return;

  cvt_gate<<<37488, 256, 0, stream>>>(x, xc, xp, fc1w, w1, fc2w, w2, aiw, wai, aow, wao,
                                      gpair, bbias, rstar, wstar);
  gemm_f1<<<2736, 256, 0, stream>>>(xp, w1, fc1b, hb, xc, wai, aib, hid);
  gemm_f2<<<738, 256, 0, stream>>>(hb, w2, fc2b, out, hid, wao, aob, rstar, wstar);
}

// Round 13
// 231.552 us; speedup vs baseline: 2.8352x; 1.0118x over previous
//
#include <hip/hip_runtime.h>
#include <hip/hip_bf16.h>

// Mlp_moe: patch MLP + 6-class 2-route MoE on cls tokens.
// Round 13: tail-backfill fusion — w2/wao f32->bf16 conversions (needed only by gemm_f2)
// moved to the END of gemm_f1's grid, filling its underfilled last residency round.
// fc1 XCD swizzle reverted (dur-neutral, fetch-negative in round 12). Rest locked.

typedef __bf16 bf16x8 __attribute__((ext_vector_type(8)));
typedef float f32x4 __attribute__((ext_vector_type(4)));
typedef unsigned short u16;

#define DEVINL __device__ __forceinline__

DEVINL u16 f2bf(float f) {  // native cast: RNE, compiler may pack as v_cvt_pk_bf16_f32
  __bf16 h = (__bf16)f;
  return __builtin_bit_cast(u16, h);
}

// Winitzki erf: abs err ~2e-4 (vs bf16 rounding 0.008), branch-free.
DEVINL float gelu_fast(float v) {
  const float x2 = 0.5f * v * v;
  const float t = x2 * (1.27323954f + 0.147f * x2) / (1.0f + 0.147f * x2);
  const float r = sqrtf(fmaxf(1.0f - __expf(-t), 0.0f));
  const float e = copysignf(r, v);
  return 0.5f * v * (1.0f + e);
}

DEVINL void async_load16(const void* g, void* l) {
  __builtin_amdgcn_global_load_lds(
      (const __attribute__((address_space(1))) unsigned int*)g,
      (__attribute__((address_space(3))) unsigned int*)l, 16, 0, 0);
}

#define MFMA16 __builtin_amdgcn_mfma_f32_16x16x32_bf16

// ---------------- dispatch 1: x split + w1/wai cvt + gate ----------------
// blocks [0,9744): x split; [9744,12048): w1; [12048,23568): wai; [23568,23664): gate.
__global__ void cvt_gate(const float* __restrict__ x, u16* __restrict__ xc, u16* __restrict__ xp,
                         const float* __restrict__ fc1w, u16* __restrict__ w1,
                         const float* __restrict__ aiw, u16* __restrict__ wai,
                         const float* __restrict__ gate_pair,
                         const float* __restrict__ balance_bias,
                         int* __restrict__ rstar, float* __restrict__ wstar) {
  int b = blockIdx.x;
  if (b < 9744) {
    const int e = (b * 256 + threadIdx.x) * 4;
    const int t = e / 768, dd = e % 768;
    const int bb = t / 203, i = t % 203;
    const float4 v = *(const float4*)(x + e);
    ushort4 u;
    u.x = f2bf(v.x); u.y = f2bf(v.y); u.z = f2bf(v.z); u.w = f2bf(v.w);
    if (i < 6) *(ushort4*)(xc + (size_t)(bb * 6 + i) * 768 + dd) = u;
    else       *(ushort4*)(xp + (size_t)(bb * 197 + (i - 6)) * 768 + dd) = u;
    return;
  }
  b -= 9744;
  if (b < 13824) {
    const float* s; u16* d;
    if (b < 2304) { s = fc1w; d = w1; }
    else { s = aiw; d = wai; b -= 2304; }
    const int i = (b * 256 + threadIdx.x) * 4;
    const float4 v = *(const float4*)(s + i);
    ushort4 u;
    u.x = f2bf(v.x); u.y = f2bf(v.y); u.z = f2bf(v.z); u.w = f2bf(v.w);
    *(ushort4*)(d + i) = u;
    return;
  }
  b -= 13824;  // gate: 96 blocks x 4 waves
  const int lane = threadIdx.x & 63, wid = threadIdx.x >> 6;
  const int idx = b * 4 + wid;
  const int bb = idx / 6, n = idx % 6;
  const float* xv = x + (size_t)(bb * 203 + n) * 768;
  const float* w0 = gate_pair + (size_t)(n * 2 + 0) * 768;
  const float* w1g = gate_pair + (size_t)(n * 2 + 1) * 768;
  double xx = 0, a00 = 0, a11 = 0, p0 = 0, p1 = 0;
  for (int d = lane; d < 768; d += 64) {
    double xd = xv[d], g0 = w0[d], g1 = w1g[d];
    xx += xd * xd; a00 += g0 * g0; a11 += g1 * g1; p0 += xd * g0; p1 += xd * g1;
  }
#pragma unroll
  for (int off = 32; off; off >>= 1) {
    xx  += __shfl_xor(xx, off);
    a00 += __shfl_xor(a00, off);
    a11 += __shfl_xor(a11, off);
    p0  += __shfl_xor(p0, off);
    p1  += __shfl_xor(p1, off);
  }
  if (lane == 0) {
    double nx = fmax(sqrt(xx), 1e-12), n0 = fmax(sqrt(a00), 1e-12), n1 = fmax(sqrt(a11), 1e-12);
    double l0 = p0 / (nx * n0) + (double)balance_bias[n * 2 + 0];
    double l1 = p1 / (nx * n1) + (double)balance_bias[n * 2 + 1];
    const int r = (l1 > l0) ? 1 : 0;
    double m = fmax(l0, l1);
    double e0 = exp(l0 - m), e1 = exp(l1 - m);
    rstar[idx] = r;
    wstar[idx] = (float)(((r == 1) ? e1 : e0) / (e0 + e1));
  }
}

// ---------------- round-1 gemm body (best measured) ----------------
template <int EPI>
DEVINL void gemm_body(const u16* __restrict__ A, const u16* __restrict__ B,
                      const float* __restrict__ bias, void* __restrict__ Cout,
                      int M, int K, int ldc, int bx, int by, u16* As, u16* Bs) {
  const int tid = threadIdx.x;
  const int lane = tid & 63, wid = tid >> 6;
  const int wr = wid >> 1, wc = wid & 1;
  const int tm = by * 128, tn = bx * 128;
  const int rA = lane >> 3, sA = lane & 7;
  const int ksteps = K >> 6;

  f32x4 acc[4][4] = {};

  for (int ks = 0; ks < ksteps; ++ks) {
    const int k0 = ks << 6;
#pragma unroll
    for (int c = 0; c < 4; ++c) {
      const int chunk = wid * 4 + c;
      const int row   = chunk * 8 + rA;
      int grow = tm + row;
      grow = grow < M ? grow : (M - 1);  // clamp tail rows (never stored)
      const int slot = sA ^ (row & 7);
      async_load16(A + (size_t)grow * K + k0 + slot * 8, (char*)As + chunk * 1024);
    }
#pragma unroll
    for (int c = 0; c < 4; ++c) {
      const int chunk = wid * 4 + c;
      const int row   = chunk * 8 + rA;
      const int slot  = sA ^ (row & 7);
      async_load16(B + (size_t)(tn + row) * K + k0 + slot * 8, (char*)Bs + chunk * 1024);
    }
    __syncthreads();  // vmcnt(0) drain: staged data visible
#pragma unroll
    for (int kk = 0; kk < 2; ++kk) {
      bf16x8 af[4], bfv[4];
#pragma unroll
      for (int im = 0; im < 4; ++im) {
        const int R = wr * 64 + im * 16 + (lane & 15);
        const int s = (kk * 4 + (lane >> 4)) ^ (R & 7);
        af[im] = *(const bf16x8*)((const char*)As + R * 128 + s * 16);
      }
#pragma unroll
      for (int in_ = 0; in_ < 4; ++in_) {
        const int R = wc * 64 + in_ * 16 + (lane & 15);
        const int s = (kk * 4 + (lane >> 4)) ^ (R & 7);
        bfv[in_] = *(const bf16x8*)((const char*)Bs + R * 128 + s * 16);
      }
#pragma unroll
      for (int im = 0; im < 4; ++im)
#pragma unroll
        for (int in_ = 0; in_ < 4; ++in_)
          acc[im][in_] = MFMA16(af[im], bfv[in_], acc[im][in_], 0, 0, 0);
    }
    __syncthreads();  // protect single buffer
  }

  const int cn = lane & 15, cr4 = (lane >> 4) * 4;
  const int col0 = tn + wc * 64 + cn;
  const int r0 = tm + wr * 64;
  int b197 = 0, p197 = 0;
  if (EPI == 1) { b197 = r0 / 197; p197 = r0 % 197; }
#pragma unroll
  for (int im = 0; im < 4; ++im) {
#pragma unroll
    for (int in_ = 0; in_ < 4; ++in_) {
      const int col = col0 + in_ * 16;
      const float bv = bias[col];
#pragma unroll
      for (int j = 0; j < 4; ++j) {
        const int off = im * 16 + cr4 + j;
        const int row = r0 + off;
        if (row < M) {
          const float v = acc[im][in_][j] + bv;
          if (EPI == 0) {
            ((u16*)Cout)[(size_t)row * ldc + col] = f2bf(gelu_fast(v));
          } else {
            int pp = p197 + off, bb = b197;
            if (pp >= 197) { pp -= 197; ++bb; }
            ((float*)Cout)[((size_t)(bb * 203 + 6 + pp)) * 768 + col] = v;
          }
        }
      }
    }
  }
}

// ---------------- round-7 cand body (32x128 tile, dbuf 2-phase) ----------------
DEVINL void cand_body(const u16* __restrict__ hid, const u16* __restrict__ wao,
                      const float* __restrict__ bout, const int* __restrict__ rstar,
                      const float* __restrict__ wstar, float* __restrict__ out,
                      int bx, int g, int bz, char* smem) {
  const int n = g >> 1, r = g & 1;
  const int src_a = (r == 0) ? (n >> 1) : (3 + (n & 1));
  const int dst_a = (r == 1) ? (n >> 1) : (3 + (n & 1));
  const int tn = bx * 128;
  const int b0 = bz * 32;
  const int tid = threadIdx.x, lane = tid & 63, wid = tid >> 6;
  const u16* Bbase = wao + (size_t)dst_a * 768 * 3072;
  const u16* Abase = hid + (size_t)src_a * 3072 + (size_t)n * 15360;

  f32x4 acc[2][2] = {};

  auto stage = [&](int buf, int t) {
    const int k0 = t << 6;
    {
      const int row = tid >> 3;
      const int slA = (tid & 7) ^ (row & 7);
      async_load16(Abase + (size_t)(b0 + row) * 6 * 15360 + k0 + slA * 8,
                   smem + buf * 4096 + row * 128 + (tid & 7) * 16);
    }
#pragma unroll
    for (int j = 0; j < 4; ++j) {
      const int row = j * 32 + (tid >> 3);
      const int slB = (tid & 7) ^ (row & 7);
      async_load16(Bbase + (size_t)(tn + row) * 3072 + k0 + slB * 8,
                   smem + 8192 + buf * 16384 + row * 128 + (tid & 7) * 16);
    }
  };
  auto compute = [&](int buf) {
    const u16* as = (const u16*)(smem + buf * 4096);
    const u16* bs = (const u16*)(smem + 8192 + buf * 16384);
#pragma unroll
    for (int kk = 0; kk < 2; ++kk) {
      bf16x8 af[2], bfv[2];
#pragma unroll
      for (int im = 0; im < 2; ++im) {
        const int R = im * 16 + (lane & 15);
        const int s = (kk * 4 + (lane >> 4)) ^ (R & 7);
        af[im] = *(const bf16x8*)(as + R * 64 + s * 8);
      }
#pragma unroll
      for (int q = 0; q < 2; ++q) {
        const int R = wid * 32 + q * 16 + (lane & 15);
        const int s = (kk * 4 + (lane >> 4)) ^ (R & 7);
        bfv[q] = *(const bf16x8*)(bs + R * 64 + s * 8);
      }
#pragma unroll
      for (int im = 0; im < 2; ++im)
#pragma unroll
        for (int q = 0; q < 2; ++q)
          acc[im][q] = MFMA16(af[im], bfv[q], acc[im][q], 0, 0, 0);
    }
  };

  stage(0, 0);
  __syncthreads();
  for (int t = 0; t < 48; ++t) {
    if (t + 1 < 48) stage((t + 1) & 1, t + 1);
    compute(t & 1);
    __syncthreads();
  }

  const int cn = lane & 15, cr4 = (lane >> 4) * 4;
#pragma unroll
  for (int im = 0; im < 2; ++im)
#pragma unroll
    for (int q = 0; q < 2; ++q) {
      const int col = tn + wid * 32 + q * 16 + cn;
      const float bv = bout[dst_a * 768 + col];
#pragma unroll
      for (int j = 0; j < 4; ++j) {
        const int b = b0 + im * 16 + cr4 + j;
        const int idx = b * 6 + n;
        if (rstar[idx] == r)
          out[((size_t)(b * 203 + n)) * 768 + col] = (acc[im][q][j] + bv) * wstar[idx];
      }
    }
}

// ---------------- dispatch 2: fc1 (2376) + hid (360) + w2/wao cvt backfill (13824) ----------------
__global__ __launch_bounds__(256, 2) void gemm_f1(
    const u16* __restrict__ xp, const u16* __restrict__ w1, const float* __restrict__ fc1b,
    u16* __restrict__ hb,
    const u16* __restrict__ xc, const u16* __restrict__ wai, const float* __restrict__ aib,
    u16* __restrict__ hidb,
    const float* __restrict__ fc2w, u16* __restrict__ w2,
    const float* __restrict__ aow, u16* __restrict__ wao) {
  __shared__ u16 As[128 * 64];
  __shared__ u16 Bs[128 * 64];
  int id = blockIdx.x;
  if (id < 2376) {
    gemm_body<0>(xp, w1, fc1b, hb, 12608, 768, 3072, id % 24, id / 24, As, Bs);
  } else if (id < 2736) {
    id -= 2376;
    gemm_body<0>(xc, wai, aib, hidb, 384, 768, 15360, id % 120, id / 120, As, Bs);
  } else {
    // w2 (2304 blocks) + wao (11520 blocks) conversions: consumed only by gemm_f2,
    // placed last so they backfill this dispatch's underfilled final residency round.
    id -= 2736;
    const float* s; u16* d;
    if (id < 2304) { s = fc2w; d = w2; }
    else { s = aow; d = wao; id -= 2304; }
    const int i = (id * 256 + threadIdx.x) * 4;
    const float4 v = *(const float4*)(s + i);
    ushort4 u;
    u.x = f2bf(v.x); u.y = f2bf(v.y); u.z = f2bf(v.z); u.w = f2bf(v.w);
    *(ushort4*)(d + i) = u;
  }
}

// ---------------- dispatch 3: fc2 (594, XCD-swizzled) + cand (144) ----------------
__global__ __launch_bounds__(256, 2) void gemm_f2(
    const u16* __restrict__ hb, const u16* __restrict__ w2, const float* __restrict__ fc2b,
    float* __restrict__ out,
    const u16* __restrict__ hidb, const u16* __restrict__ wao, const float* __restrict__ aob,
    const int* __restrict__ rstar, const float* __restrict__ wstar) {
  __shared__ char smem[40960];
  int id = blockIdx.x;
  if (id < 594) {
    // m204 bijective chunking for nwg=594: q=74, r=2
    const int xcd = id & 7, k = id >> 3;
    id = (xcd < 2 ? xcd * 75 : 150 + (xcd - 2) * 74) + k;
    gemm_body<1>(hb, w2, fc2b, out, 12608, 3072, 768, id % 6, id / 6,
                 (u16*)smem, (u16*)(smem + 16384));
  } else {
    id -= 594;
    cand_body(hidb, wao, aob, rstar, wstar, out, id % 6, (id / 6) % 12, id / 72, smem);
  }
}

// ---------------- launch ----------------
extern "C" void kernel_launch(void* const* d_in, const int* in_sizes, int n_in,
                              void* d_out, int out_size, void* d_ws, size_t ws_size,
                              hipStream_t stream) {
  const float* x     = (const float*)d_in[0];
  const float* fc1w  = (const float*)d_in[1];
  const float* fc1b  = (const float*)d_in[2];
  const float* fc2w  = (const float*)d_in[3];
  const float* fc2b  = (const float*)d_in[4];
  const float* gpair = (const float*)d_in[5];
  const float* aiw   = (const float*)d_in[6];
  const float* aib   = (const float*)d_in[7];
  const float* aow   = (const float*)d_in[8];
  const float* aob   = (const float*)d_in[9];
  const float* bbias = (const float*)d_in[10];
  float* out = (float*)d_out;

  char* ws = (char*)d_ws;
  u16* xp   = (u16*)(ws + 0);          // 12608x768 bf16
  u16* xc   = (u16*)(ws + 19365888);   // 384x768
  u16* w1   = (u16*)(ws + 19955712);   // 3072x768
  u16* w2   = (u16*)(ws + 24674304);   // 768x3072
  u16* wai  = (u16*)(ws + 29392896);   // 5x3072x768
  u16* wao  = (u16*)(ws + 52985856);   // 5x768x3072
  u16* hb   = (u16*)(ws + 76578816);   // 12608x3072
  u16* hid  = (u16*)(ws + 154042368);  // 384x15360
  int*   rstar = (int*)(ws + 165838848);
  float* wstar = (float*)(ws + 165840384);
  if (ws_size < 165841920) return;

  // dispatch 1: x split + w1/wai cvt + gate (23664 blocks)
  cvt_gate<<<23664, 256, 0, stream>>>(x, xc, xp, fc1w, w1, aiw, wai,
                                      gpair, bbias, rstar, wstar);
  // dispatch 2: fc1 + hid_all + w2/wao cvt backfill (16560 blocks)
  gemm_f1<<<16560, 256, 0, stream>>>(xp, w1, fc1b, hb, xc, wai, aib, hid,
                                     fc2w, w2, aow, wao);
  // dispatch 3: fc2 + route candidates (738 blocks)
  gemm_f2<<<738, 256, 0, stream>>>(hb, w2, fc2b, out, hid, wao, aob, rstar, wstar);
}